// Round 6
// baseline (301.950 us; speedup 1.0000x reference)
//
#include <hip/hip_runtime.h>

// VQ-VAE vector quantizer. Round 6.
// z: [16,64,32,32] f32, emb: [8192,64] f32. N=16384 pts, C=64, V=8192.
// out = [ z_q_st (1048576) | idx as f32 (16384) | vq_loss (1) ]
//
// R5 post-mortem: k_rescue was a serial latency chain (3 dependent shfl_xor
// ~120cyc each per iteration, 1 wave/SIMD -> no hiding) = 107us at 20% VALU.
// R6: k_pre also writes embT (fp32 transposed [c][v]); rescue gives each
// thread 32 PRIVATE codes (float4 loads of embT, coalesced), z via LDS
// broadcast -> no cross-lane ops in the hot loop, 32 independent FMA chains.

typedef _Float16 half8 __attribute__((ext_vector_type(8)));
typedef float f32x4 __attribute__((ext_vector_type(4)));

#define N_PTS 16384
#define SPLITS 4
#define THR 0.08f

// e16 swizzled (halfs): off(v,c) = (v>>4)*1024 + (c>>5)*512
//                                   + ((c>>3)&3)*128 + (v&15)*8 + (c&7)
// -> per-wave B-frag load (tile T, half H): e16 + T*1024 + H*512 + lane*8,
//    contiguous 1KB, giving B[n=lane&15][k=(lane>>4)*8+j].

// ---------------- k_pre: emb -> swizzled fp16 + fp32 transpose, norms --------
__global__ __launch_bounds__(256) void k_pre(const float* __restrict__ emb,
                                             float* __restrict__ h,
                                             unsigned short* __restrict__ e16,
                                             float* __restrict__ embT,
                                             int* __restrict__ cnt) {
  int v = blockIdx.x * 256 + threadIdx.x;   // grid 32 -> 8192
  const float4* e4 = (const float4*)(emb + v * 64);
  float s = 0.f;
  float row[64];
#pragma unroll
  for (int i = 0; i < 16; ++i) {
    float4 a = e4[i];
    row[i * 4 + 0] = a.x; row[i * 4 + 1] = a.y;
    row[i * 4 + 2] = a.z; row[i * 4 + 3] = a.w;
    s += a.x * a.x + a.y * a.y + a.z * a.z + a.w * a.w;
  }
  unsigned short* base = e16 + (v >> 4) * 1024 + (v & 15) * 8;
#pragma unroll
  for (int c8 = 0; c8 < 8; ++c8) {
    half8 o;
#pragma unroll
    for (int j = 0; j < 8; ++j) o[j] = (_Float16)row[c8 * 8 + j];
    *(half8*)(base + (c8 >> 2) * 512 + (c8 & 3) * 128) = o;
  }
  // fp32 transpose: embT[c][v]; consecutive lanes -> consecutive v: coalesced
#pragma unroll
  for (int c = 0; c < 64; ++c) embT[c * 8192 + v] = row[c];
  h[v] = 0.5f * s;
  if (v == 0) *cnt = 0;
}

// ---------------- k1: 16x16x32 MFMA scores + per-split top-2 ----------------
// grid (256, 4). block 256 = 4 waves; wave owns 16 points, sweeps 2048 codes
// (128 tiles of 16). Per-lane state: 4 rows x (s1,i1,s2) = 12 regs.
__global__ __launch_bounds__(256, 4) void k1_score(
    const float* __restrict__ z, const unsigned short* __restrict__ e16,
    const float* __restrict__ h,
    float* __restrict__ ps, float* __restrict__ pi, float* __restrict__ p2) {
  const int tid = threadIdx.x;
  const int lane = tid & 63;
  const int wid = tid >> 6;
  const int cl = lane & 15;     // A row (point) / B col (code) within tile
  const int gq = lane >> 4;     // quad: selects k-slice / C rows
  const int n0 = blockIdx.x * 64 + wid * 16;
  const int split = blockIdx.y;

  const int b = n0 >> 10;
  const int hw0 = n0 & 1023;

  // A frags: A[m=cl][k=gq*8+j] (half H covers channels H*32..H*32+31)
  half8 A[2];
  {
    const float* zb = z + b * 65536 + hw0 + cl;
#pragma unroll
    for (int H = 0; H < 2; ++H) {
      half8 a;
#pragma unroll
      for (int j = 0; j < 8; ++j)
        a[j] = (_Float16)zb[(H * 32 + gq * 8 + j) * 1024];
      A[H] = a;
    }
  }

  float s1[4], i1f[4], s2[4];
#pragma unroll
  for (int r = 0; r < 4; ++r) { s1[r] = -3.0e38f; i1f[r] = 0.f; s2[r] = -3.0e38f; }

  const int vbase = split * 2048;
  const unsigned short* bbase = e16 + (vbase >> 4) * 1024 + lane * 8;

#pragma unroll 4
  for (int T = 0; T < 128; ++T) {
    const unsigned short* bp = bbase + T * 1024;
    half8 B0 = *(const half8*)bp;
    half8 B1 = *(const half8*)(bp + 512);
    const int code = vbase + T * 16 + cl;
    const float nhv = -h[code];
    const float vf = (float)code;

    f32x4 acc;
    acc[0] = nhv; acc[1] = nhv; acc[2] = nhv; acc[3] = nhv;
    acc = __builtin_amdgcn_mfma_f32_16x16x32_f16(A[0], B0, acc, 0, 0, 0);
    acc = __builtin_amdgcn_mfma_f32_16x16x32_f16(A[1], B1, acc, 0, 0, 0);

    // per-lane running top-2 for 4 rows (points), this lane's col (code)
#pragma unroll
    for (int r = 0; r < 4; ++r) {
      float sc = acc[r];
      s2[r] = fmaxf(fminf(sc, s1[r]), s2[r]);   // top2 update
      bool gt = sc > s1[r];                     // strict: first occurrence
      i1f[r] = gt ? vf : i1f[r];
      s1[r] = fmaxf(s1[r], sc);
    }
  }

  // butterfly merge across the 16 cols (lanes with same gq hold same rows)
#pragma unroll
  for (int off = 8; off >= 1; off >>= 1) {
#pragma unroll
    for (int r = 0; r < 4; ++r) {
      float os = __shfl_xor(s1[r], off);
      float oi = __shfl_xor(i1f[r], off);
      float o2 = __shfl_xor(s2[r], off);
      s2[r] = fmaxf(fmaxf(s2[r], o2), fminf(s1[r], os));
      bool gt = os > s1[r];     // exact ties -> margin 0 -> rescue resolves
      i1f[r] = gt ? oi : i1f[r];
      s1[r] = fmaxf(s1[r], os);
    }
  }

  if (cl == 0) {
#pragma unroll
    for (int r = 0; r < 4; ++r) {
      int n = n0 + gq * 4 + r;               // C row = gq*4 + reg
      int o = split * N_PTS + n;
      ps[o] = s1[r]; pi[o] = i1f[r]; p2[o] = s2[r];
    }
  }
}

// ---------------- k2: merge splits, margin test, emit idx ----------------
__global__ __launch_bounds__(256) void k2_merge(
    const float* __restrict__ ps, const float* __restrict__ pi,
    const float* __restrict__ p2,
    int* __restrict__ idxf, float* __restrict__ out_idx,
    int* __restrict__ list, int* __restrict__ cnt) {
  int n = blockIdx.x * 256 + threadIdx.x;   // grid 64 -> 16384
  float S1 = ps[n], I1 = pi[n], S2 = p2[n];
#pragma unroll
  for (int s = 1; s < SPLITS; ++s) {
    int o = s * N_PTS + n;
    float a = ps[o], ai = pi[o], a2 = p2[o];
    if (a > S1) { S2 = fmaxf(fmaxf(S2, a2), S1); S1 = a; I1 = ai; }
    else        { S2 = fmaxf(S2, a); }
  }
  idxf[n] = (int)I1;
  out_idx[n] = I1;
  if (S1 - S2 < THR) {
    int p = atomicAdd(cnt, 1);
    list[p] = n;
  }
}

// ---------------- k_rescue: exact fp32, thread-private codes ----------------
// One point per block. Thread t owns codes {s*1024 + 4t .. +3, s=0..7} via
// float4 loads of embT (coalesced); z broadcast from LDS. No cross-lane ops
// in the hot loop; 32 independent accumulator chains.
__global__ __launch_bounds__(256) void k_rescue(
    const float* __restrict__ z, const float* __restrict__ embT,
    const float* __restrict__ h, const int* __restrict__ list,
    const int* __restrict__ cnt,
    int* __restrict__ idxf, float* __restrict__ out_idx) {
  __shared__ float zs[64];
  __shared__ float rs[4], ri[4];
  const int tid = threadIdx.x;
  const int lane = tid & 63, wv = tid >> 6;
  const int count = *cnt;

  for (int p = blockIdx.x; p < count; p += gridDim.x) {
    const int n = list[p];
    const int bb = n >> 10, hw = n & 1023;
    __syncthreads();
    if (tid < 64) zs[tid] = z[bb * 65536 + tid * 1024 + hw];
    __syncthreads();

    float d[32];
#pragma unroll
    for (int i = 0; i < 32; ++i) d[i] = 0.f;

    const float4* eT = (const float4*)embT;   // [c][2048] in float4 units
#pragma unroll 4
    for (int c = 0; c < 64; ++c) {
      const float zc = zs[c];
      const float4* rowp = eT + c * 2048 + tid;
#pragma unroll
      for (int s = 0; s < 8; ++s) {
        float4 ev = rowp[s * 256];
        d[s * 4 + 0] = fmaf(ev.x, zc, d[s * 4 + 0]);
        d[s * 4 + 1] = fmaf(ev.y, zc, d[s * 4 + 1]);
        d[s * 4 + 2] = fmaf(ev.z, zc, d[s * 4 + 2]);
        d[s * 4 + 3] = fmaf(ev.w, zc, d[s * 4 + 3]);
      }
    }

    // per-thread argmax over its 32 codes, visited code-ascending (strict >)
    float bs = -3.0e38f, bi = 0.f;
#pragma unroll
    for (int s = 0; s < 8; ++s)
#pragma unroll
      for (int k = 0; k < 4; ++k) {
        int code = s * 1024 + tid * 4 + k;
        float sc = d[s * 4 + k] - h[code];
        if (sc > bs) { bs = sc; bi = (float)code; }
      }

    // wave reduce (tie -> lower code), then cross-wave via LDS
#pragma unroll
    for (int off = 32; off >= 1; off >>= 1) {
      float os = __shfl_xor(bs, off);
      float oi = __shfl_xor(bi, off);
      if (os > bs || (os == bs && oi < bi)) { bs = os; bi = oi; }
    }
    if (lane == 0) { rs[wv] = bs; ri[wv] = bi; }
    __syncthreads();
    if (tid == 0) {
      float s = rs[0], i = ri[0];
#pragma unroll
      for (int w = 1; w < 4; ++w) {
        if (rs[w] > s || (rs[w] == s && ri[w] < i)) { s = rs[w]; i = ri[w]; }
      }
      idxf[n] = (int)i;
      out_idx[n] = i;
    }
  }
}

// ---------------- k3: gather, straight-through out, block partial loss --------
__global__ __launch_bounds__(256) void k3_quant(
    const float* __restrict__ z, const float* __restrict__ emb,
    const int* __restrict__ idxf,
    float* __restrict__ out, float* __restrict__ psum) {
  int t = blockIdx.x * 256 + threadIdx.x;   // grid 1024 -> 262144 float4 slots
  int g = t * 4;
  int b = g >> 16;
  int c = (g >> 10) & 63;
  int hw = g & 1023;
  int n = (b << 10) | hw;                   // n..n+3, 4-aligned
  float4 zv = *(const float4*)(z + g);
  int4 iv = *(const int4*)(idxf + n);
  float q0 = emb[iv.x * 64 + c];
  float q1 = emb[iv.y * 64 + c];
  float q2 = emb[iv.z * 64 + c];
  float q3 = emb[iv.w * 64 + c];
  float d0 = q0 - zv.x, d1 = q1 - zv.y, d2 = q2 - zv.z, d3 = q3 - zv.w;
  float4 o;
  o.x = zv.x + d0; o.y = zv.y + d1; o.z = zv.z + d2; o.w = zv.w + d3;
  *(float4*)(out + g) = o;
  float val = d0 * d0 + d1 * d1 + d2 * d2 + d3 * d3;
#pragma unroll
  for (int off = 32; off >= 1; off >>= 1) val += __shfl_down(val, off);
  __shared__ float wsum[4];
  int lane = threadIdx.x & 63, wv = threadIdx.x >> 6;
  if (lane == 0) wsum[wv] = val;
  __syncthreads();
  if (threadIdx.x == 0)
    psum[blockIdx.x] = wsum[0] + wsum[1] + wsum[2] + wsum[3];
}

// ---------------- k4: final loss reduce (1024 partials) ----------------
__global__ __launch_bounds__(256) void k4_loss(const float* __restrict__ psum,
                                               float* __restrict__ out_loss) {
  int tid = threadIdx.x;
  float val = psum[tid] + psum[tid + 256] + psum[tid + 512] + psum[tid + 768];
#pragma unroll
  for (int off = 32; off >= 1; off >>= 1) val += __shfl_down(val, off);
  __shared__ float wsum[4];
  int lane = tid & 63, wv = tid >> 6;
  if (lane == 0) wsum[wv] = val;
  __syncthreads();
  if (tid == 0)
    out_loss[0] = 1.25f * (wsum[0] + wsum[1] + wsum[2] + wsum[3]) * (1.0f / 1048576.0f);
}

extern "C" void kernel_launch(void* const* d_in, const int* in_sizes, int n_in,
                              void* d_out, int out_size, void* d_ws, size_t ws_size,
                              hipStream_t stream) {
  const float* z   = (const float*)d_in[0];
  const float* emb = (const float*)d_in[1];
  float* out = (float*)d_out;
  float* ws  = (float*)d_ws;

  float* h   = ws;                                    // 8192
  unsigned short* e16 = (unsigned short*)(ws + 8192); // 524288 halfs = 262144 f
  float* embT = ws + 8192 + 262144;                   // 524288 (fp32 transpose)
  float* ps  = embT + 524288;                         // 4*16384
  float* pi  = ps + SPLITS * N_PTS;                   // 4*16384
  float* p2  = pi + SPLITS * N_PTS;                   // 4*16384
  int* idxf  = (int*)(p2 + SPLITS * N_PTS);           // 16384
  int* list  = idxf + N_PTS;                          // 16384
  int* cnt   = list + N_PTS;                          // 1
  float* psum = (float*)(cnt + 1);                    // 1024

  float* out_idx  = out + 1048576;
  float* out_loss = out + 1048576 + 16384;

  k_pre<<<32, 256, 0, stream>>>(emb, h, e16, embT, cnt);
  k1_score<<<dim3(256, SPLITS), 256, 0, stream>>>(z, e16, h, ps, pi, p2);
  k2_merge<<<64, 256, 0, stream>>>(ps, pi, p2, idxf, out_idx, list, cnt);
  k_rescue<<<512, 256, 0, stream>>>(z, embT, h, list, cnt, idxf, out_idx);
  k3_quant<<<1024, 256, 0, stream>>>(z, emb, idxf, out, psum);
  k4_loss<<<1, 256, 0, stream>>>(psum, out_loss);
}

// Round 7
// 158.740 us; speedup vs baseline: 1.9022x; 1.9022x over previous
//
#include <hip/hip_runtime.h>

// VQ-VAE vector quantizer. Round 7.
// z: [16,64,32,32] f32, emb: [8192,64] f32. N=16384 pts, C=64, V=8192.
// out = [ z_q_st (1048576) | idx as f32 (16384) | vq_loss (1) ]
//
// R6 post-mortem: rescue was a VMEM latency chain (72 VGPR -> loads
// serialized, 1 wave/SIMD, ~400cyc L2 waits) = 183us at 4% VALU. k1 is
// L1-ingest-bound: 16 waves/CU x 256KB/wave / 64B/cyc ~= 27us.
// R7: rescue batches 4 points/block (d[32][4]=128 VGPR accs, launch_bounds
// (256,1), no cross-lane in hot loop) -> L1-bound ~13us. k1 reuses each
// B-frag for 2 point-tiles -> per-CU ingest halves -> ~14us.

typedef _Float16 half8 __attribute__((ext_vector_type(8)));
typedef float f32x4 __attribute__((ext_vector_type(4)));

#define N_PTS 16384
#define SPLITS 4
#define THR 0.08f

// e16 swizzled (halfs): off(v,c) = (v>>4)*1024 + (c>>5)*512
//                                   + ((c>>3)&3)*128 + (v&15)*8 + (c&7)
// -> per-wave B-frag load (tile T, half H): e16 + T*1024 + H*512 + lane*8,
//    contiguous 1KB, giving B[n=lane&15][k=(lane>>4)*8+j].

// ---------------- k_pre: emb -> swizzled fp16 + fp32 transpose, norms --------
__global__ __launch_bounds__(256) void k_pre(const float* __restrict__ emb,
                                             float* __restrict__ h,
                                             unsigned short* __restrict__ e16,
                                             float* __restrict__ embT,
                                             int* __restrict__ cnt) {
  int v = blockIdx.x * 256 + threadIdx.x;   // grid 32 -> 8192
  const float4* e4 = (const float4*)(emb + v * 64);
  float s = 0.f;
  float row[64];
#pragma unroll
  for (int i = 0; i < 16; ++i) {
    float4 a = e4[i];
    row[i * 4 + 0] = a.x; row[i * 4 + 1] = a.y;
    row[i * 4 + 2] = a.z; row[i * 4 + 3] = a.w;
    s += a.x * a.x + a.y * a.y + a.z * a.z + a.w * a.w;
  }
  unsigned short* base = e16 + (v >> 4) * 1024 + (v & 15) * 8;
#pragma unroll
  for (int c8 = 0; c8 < 8; ++c8) {
    half8 o;
#pragma unroll
    for (int j = 0; j < 8; ++j) o[j] = (_Float16)row[c8 * 8 + j];
    *(half8*)(base + (c8 >> 2) * 512 + (c8 & 3) * 128) = o;
  }
  // fp32 transpose: embT[c][v]; consecutive lanes -> consecutive v: coalesced
#pragma unroll
  for (int c = 0; c < 64; ++c) embT[c * 8192 + v] = row[c];
  h[v] = 0.5f * s;
  if (v == 0) *cnt = 0;
}

// ---------------- k1: 16x16x32 MFMA scores, 2 point-tiles per wave ----------
// grid (128, 4). block 256 = 4 waves; wave owns 32 points (2 tiles of 16),
// sweeps 2048 codes (128 tiles). B-frags loaded once per code-tile, used for
// both point-tiles -> per-point L1 ingest halved vs R5.
__global__ __launch_bounds__(256, 2) void k1_score(
    const float* __restrict__ z, const unsigned short* __restrict__ e16,
    const float* __restrict__ h,
    float* __restrict__ ps, float* __restrict__ pi, float* __restrict__ p2) {
  const int tid = threadIdx.x;
  const int lane = tid & 63;
  const int wid = tid >> 6;
  const int cl = lane & 15;     // A row (point) / B col (code) within tile
  const int gq = lane >> 4;     // quad: selects k-slice / C rows
  const int n0 = blockIdx.x * 128 + wid * 32;
  const int split = blockIdx.y;

  const int b = n0 >> 10;
  const int hw0 = n0 & 1023;

  // A frags: A[pt][H]  with A[m=cl][k=gq*8+j], half H = channels H*32..+31
  half8 A[2][2];
  {
    const float* zb = z + b * 65536 + hw0 + cl;
#pragma unroll
    for (int pt = 0; pt < 2; ++pt)
#pragma unroll
      for (int H = 0; H < 2; ++H) {
        half8 a;
#pragma unroll
        for (int j = 0; j < 8; ++j)
          a[j] = (_Float16)zb[pt * 16 + (H * 32 + gq * 8 + j) * 1024];
        A[pt][H] = a;
      }
  }

  float s1[2][4], i1f[2][4], s2[2][4];
#pragma unroll
  for (int pt = 0; pt < 2; ++pt)
#pragma unroll
    for (int r = 0; r < 4; ++r) {
      s1[pt][r] = -3.0e38f; i1f[pt][r] = 0.f; s2[pt][r] = -3.0e38f;
    }

  const int vbase = split * 2048;
  const unsigned short* bbase = e16 + (vbase >> 4) * 1024 + lane * 8;

#pragma unroll 2
  for (int T = 0; T < 128; ++T) {
    const unsigned short* bp = bbase + T * 1024;
    half8 B0 = *(const half8*)bp;
    half8 B1 = *(const half8*)(bp + 512);
    const int code = vbase + T * 16 + cl;
    const float nhv = -h[code];
    const float vf = (float)code;

#pragma unroll
    for (int pt = 0; pt < 2; ++pt) {
      f32x4 acc;
      acc[0] = nhv; acc[1] = nhv; acc[2] = nhv; acc[3] = nhv;
      acc = __builtin_amdgcn_mfma_f32_16x16x32_f16(A[pt][0], B0, acc, 0, 0, 0);
      acc = __builtin_amdgcn_mfma_f32_16x16x32_f16(A[pt][1], B1, acc, 0, 0, 0);

      // per-lane running top-2 for 4 rows (points), this lane's col (code)
#pragma unroll
      for (int r = 0; r < 4; ++r) {
        float sc = acc[r];
        s2[pt][r] = fmaxf(fminf(sc, s1[pt][r]), s2[pt][r]);
        bool gt = sc > s1[pt][r];               // strict: first occurrence
        i1f[pt][r] = gt ? vf : i1f[pt][r];
        s1[pt][r] = fmaxf(s1[pt][r], sc);
      }
    }
  }

  // butterfly merge across the 16 cols (lanes with same gq hold same rows)
#pragma unroll
  for (int off = 8; off >= 1; off >>= 1) {
#pragma unroll
    for (int pt = 0; pt < 2; ++pt)
#pragma unroll
      for (int r = 0; r < 4; ++r) {
        float os = __shfl_xor(s1[pt][r], off);
        float oi = __shfl_xor(i1f[pt][r], off);
        float o2 = __shfl_xor(s2[pt][r], off);
        s2[pt][r] = fmaxf(fmaxf(s2[pt][r], o2), fminf(s1[pt][r], os));
        bool gt = os > s1[pt][r];   // exact ties -> margin 0 -> rescue
        i1f[pt][r] = gt ? oi : i1f[pt][r];
        s1[pt][r] = fmaxf(s1[pt][r], os);
      }
  }

  if (cl == 0) {
#pragma unroll
    for (int pt = 0; pt < 2; ++pt)
#pragma unroll
      for (int r = 0; r < 4; ++r) {
        int n = n0 + pt * 16 + gq * 4 + r;     // C row = gq*4 + reg
        int o = split * N_PTS + n;
        ps[o] = s1[pt][r]; pi[o] = i1f[pt][r]; p2[o] = s2[pt][r];
      }
  }
}

// ---------------- k2: merge splits, margin test, emit idx ----------------
__global__ __launch_bounds__(256) void k2_merge(
    const float* __restrict__ ps, const float* __restrict__ pi,
    const float* __restrict__ p2,
    int* __restrict__ idxf, float* __restrict__ out_idx,
    int* __restrict__ list, int* __restrict__ cnt) {
  int n = blockIdx.x * 256 + threadIdx.x;   // grid 64 -> 16384
  float S1 = ps[n], I1 = pi[n], S2 = p2[n];
#pragma unroll
  for (int s = 1; s < SPLITS; ++s) {
    int o = s * N_PTS + n;
    float a = ps[o], ai = pi[o], a2 = p2[o];
    if (a > S1) { S2 = fmaxf(fmaxf(S2, a2), S1); S1 = a; I1 = ai; }
    else        { S2 = fmaxf(S2, a); }
  }
  idxf[n] = (int)I1;
  out_idx[n] = I1;
  if (S1 - S2 < THR) {
    int p = atomicAdd(cnt, 1);
    list[p] = n;
  }
}

// ---------------- k_rescue: exact fp32, 4 points/block, private codes --------
// Thread t owns 32 codes (8 float4 of embT); 4 points share the sweep.
// d[32 codes][4 pts] = 128 VGPR accumulators; z via broadcast ds_read_b128.
// No cross-lane ops in the hot loop.
__global__ __launch_bounds__(256, 1) void k_rescue(
    const float* __restrict__ z, const float* __restrict__ embT,
    const float* __restrict__ h, const int* __restrict__ list,
    const int* __restrict__ cnt,
    int* __restrict__ idxf, float* __restrict__ out_idx) {
  __shared__ float zsT[64][4];
  __shared__ int pn[4];
  __shared__ float rs[4][4], ri[4][4];
  const int tid = threadIdx.x;
  const int lane = tid & 63, wv = tid >> 6;
  const int count = *cnt;

  for (int base = blockIdx.x * 4; base < count; base += gridDim.x * 4) {
    const int P = min(4, count - base);
    __syncthreads();
    if (tid < 4) pn[tid] = list[base + min(tid, P - 1)];  // pad with last valid
    __syncthreads();
    {
      int p = tid >> 6, c = tid & 63;
      int n = pn[p];
      zsT[c][p] = z[(n >> 10) * 65536 + c * 1024 + (n & 1023)];
    }
    __syncthreads();

    float d[128];
#pragma unroll
    for (int i = 0; i < 128; ++i) d[i] = 0.f;

    const float4* eT = (const float4*)embT;   // [c][2048] float4 units
    for (int c = 0; c < 64; ++c) {
      float4 zp = *(const float4*)&zsT[c][0];     // broadcast, conflict-free
      const float4* rowp = eT + c * 2048 + tid;
#pragma unroll
      for (int s = 0; s < 8; ++s) {
        float4 ev = rowp[s * 256];
        float* dp = d + s * 16;
        dp[0]  = fmaf(ev.x, zp.x, dp[0]);  dp[1]  = fmaf(ev.x, zp.y, dp[1]);
        dp[2]  = fmaf(ev.x, zp.z, dp[2]);  dp[3]  = fmaf(ev.x, zp.w, dp[3]);
        dp[4]  = fmaf(ev.y, zp.x, dp[4]);  dp[5]  = fmaf(ev.y, zp.y, dp[5]);
        dp[6]  = fmaf(ev.y, zp.z, dp[6]);  dp[7]  = fmaf(ev.y, zp.w, dp[7]);
        dp[8]  = fmaf(ev.z, zp.x, dp[8]);  dp[9]  = fmaf(ev.z, zp.y, dp[9]);
        dp[10] = fmaf(ev.z, zp.z, dp[10]); dp[11] = fmaf(ev.z, zp.w, dp[11]);
        dp[12] = fmaf(ev.w, zp.x, dp[12]); dp[13] = fmaf(ev.w, zp.y, dp[13]);
        dp[14] = fmaf(ev.w, zp.z, dp[14]); dp[15] = fmaf(ev.w, zp.w, dp[15]);
      }
    }

    // per-thread argmax per point over its 32 codes (code-ascending, strict >)
    float bs[4], bi[4];
#pragma unroll
    for (int p = 0; p < 4; ++p) { bs[p] = -3.0e38f; bi[p] = 0.f; }
#pragma unroll
    for (int s = 0; s < 8; ++s) {
      float4 hv = *(const float4*)(h + s * 1024 + tid * 4);
#pragma unroll
      for (int k = 0; k < 4; ++k) {
        float hk = (k == 0) ? hv.x : (k == 1) ? hv.y : (k == 2) ? hv.z : hv.w;
        float cf = (float)(s * 1024 + tid * 4 + k);
#pragma unroll
        for (int p = 0; p < 4; ++p) {
          float sc = d[s * 16 + k * 4 + p] - hk;
          if (sc > bs[p]) { bs[p] = sc; bi[p] = cf; }
        }
      }
    }

    // wave butterfly (disjoint code sets; tie -> lower code), then cross-wave
#pragma unroll
    for (int off = 32; off >= 1; off >>= 1) {
#pragma unroll
      for (int p = 0; p < 4; ++p) {
        float os = __shfl_xor(bs[p], off);
        float oi = __shfl_xor(bi[p], off);
        if (os > bs[p] || (os == bs[p] && oi < bi[p])) { bs[p] = os; bi[p] = oi; }
      }
    }
    if (lane == 0)
#pragma unroll
      for (int p = 0; p < 4; ++p) { rs[wv][p] = bs[p]; ri[wv][p] = bi[p]; }
    __syncthreads();
    if (tid < 4) {
      int p = tid;
      float s = rs[0][p], i = ri[0][p];
#pragma unroll
      for (int w = 1; w < 4; ++w) {
        if (rs[w][p] > s || (rs[w][p] == s && ri[w][p] < i)) { s = rs[w][p]; i = ri[w][p]; }
      }
      if (p < P) {
        int n = pn[p];
        idxf[n] = (int)i;
        out_idx[n] = i;
      }
    }
  }
}

// ---------------- k3: gather, straight-through out, block partial loss --------
__global__ __launch_bounds__(256) void k3_quant(
    const float* __restrict__ z, const float* __restrict__ emb,
    const int* __restrict__ idxf,
    float* __restrict__ out, float* __restrict__ psum) {
  int t = blockIdx.x * 256 + threadIdx.x;   // grid 1024 -> 262144 float4 slots
  int g = t * 4;
  int b = g >> 16;
  int c = (g >> 10) & 63;
  int hw = g & 1023;
  int n = (b << 10) | hw;                   // n..n+3, 4-aligned
  float4 zv = *(const float4*)(z + g);
  int4 iv = *(const int4*)(idxf + n);
  float q0 = emb[iv.x * 64 + c];
  float q1 = emb[iv.y * 64 + c];
  float q2 = emb[iv.z * 64 + c];
  float q3 = emb[iv.w * 64 + c];
  float d0 = q0 - zv.x, d1 = q1 - zv.y, d2 = q2 - zv.z, d3 = q3 - zv.w;
  float4 o;
  o.x = zv.x + d0; o.y = zv.y + d1; o.z = zv.z + d2; o.w = zv.w + d3;
  *(float4*)(out + g) = o;
  float val = d0 * d0 + d1 * d1 + d2 * d2 + d3 * d3;
#pragma unroll
  for (int off = 32; off >= 1; off >>= 1) val += __shfl_down(val, off);
  __shared__ float wsum[4];
  int lane = threadIdx.x & 63, wv = threadIdx.x >> 6;
  if (lane == 0) wsum[wv] = val;
  __syncthreads();
  if (threadIdx.x == 0)
    psum[blockIdx.x] = wsum[0] + wsum[1] + wsum[2] + wsum[3];
}

// ---------------- k4: final loss reduce (1024 partials) ----------------
__global__ __launch_bounds__(256) void k4_loss(const float* __restrict__ psum,
                                               float* __restrict__ out_loss) {
  int tid = threadIdx.x;
  float val = psum[tid] + psum[tid + 256] + psum[tid + 512] + psum[tid + 768];
#pragma unroll
  for (int off = 32; off >= 1; off >>= 1) val += __shfl_down(val, off);
  __shared__ float wsum[4];
  int lane = tid & 63, wv = tid >> 6;
  if (lane == 0) wsum[wv] = val;
  __syncthreads();
  if (tid == 0)
    out_loss[0] = 1.25f * (wsum[0] + wsum[1] + wsum[2] + wsum[3]) * (1.0f / 1048576.0f);
}

extern "C" void kernel_launch(void* const* d_in, const int* in_sizes, int n_in,
                              void* d_out, int out_size, void* d_ws, size_t ws_size,
                              hipStream_t stream) {
  const float* z   = (const float*)d_in[0];
  const float* emb = (const float*)d_in[1];
  float* out = (float*)d_out;
  float* ws  = (float*)d_ws;

  float* h   = ws;                                    // 8192
  unsigned short* e16 = (unsigned short*)(ws + 8192); // 524288 halfs = 262144 f
  float* embT = ws + 8192 + 262144;                   // 524288 (fp32 transpose)
  float* ps  = embT + 524288;                         // 4*16384
  float* pi  = ps + SPLITS * N_PTS;                   // 4*16384
  float* p2  = pi + SPLITS * N_PTS;                   // 4*16384
  int* idxf  = (int*)(p2 + SPLITS * N_PTS);           // 16384
  int* list  = idxf + N_PTS;                          // 16384
  int* cnt   = list + N_PTS;                          // 1
  float* psum = (float*)(cnt + 1);                    // 1024

  float* out_idx  = out + 1048576;
  float* out_loss = out + 1048576 + 16384;

  k_pre<<<32, 256, 0, stream>>>(emb, h, e16, embT, cnt);
  k1_score<<<dim3(128, SPLITS), 256, 0, stream>>>(z, e16, h, ps, pi, p2);
  k2_merge<<<64, 256, 0, stream>>>(ps, pi, p2, idxf, out_idx, list, cnt);
  k_rescue<<<512, 256, 0, stream>>>(z, embT, h, list, cnt, idxf, out_idx);
  k3_quant<<<1024, 256, 0, stream>>>(z, emb, idxf, out, psum);
  k4_loss<<<1, 256, 0, stream>>>(psum, out_loss);
}